// Round 16
// baseline (175.591 us; speedup 1.0000x reference)
//
#include <hip/hip_runtime.h>

#define N_NODES 50000
#define N_EDGES 800000
#define D 128
#define CAP 128           // bucket capacity (pairs/row); deg~Poisson(16), P(>=128)~e^-100

typedef __attribute__((ext_vector_type(8))) short bf16x8;
typedef __attribute__((ext_vector_type(4))) float f32x4;
typedef __attribute__((ext_vector_type(4))) short short4v;

__device__ __forceinline__ short f2bf(float f) {
    unsigned u = __float_as_uint(f);
    unsigned r = u + 0x7FFFu + ((u >> 16) & 1u);   // RNE; inputs finite
    return (short)(r >> 16);
}
__device__ __forceinline__ float bf2f(short s) {
    return __uint_as_float(((unsigned)(unsigned short)s) << 16);
}

// ---------------------------------------------------------------------------
// Dispatch 0 (replaces memset): blocks 0..7 transpose+convert W into global
// bf16 Wt[c][k] (r11-proven neutral for gemm, and it removes ALL LDS from the
// big dispatch -> scatter blocks no longer capped at 4 blocks/CU).
// Blocks 8.. zero cnt.
// ---------------------------------------------------------------------------
__global__ __launch_bounds__(256) void prep_zero(const float* __restrict__ W,
                                                 short* __restrict__ Wt,
                                                 int* __restrict__ cnt)
{
    const int b = blockIdx.x, t = threadIdx.x;
    if (b < 8) {
        __shared__ short Ls[128][17];    // [c][kk] padded
        #pragma unroll
        for (int i = 0; i < 8; ++i) {
            int lin = i * 256 + t;       // 0..2047
            int kk = lin >> 7;           // 0..15
            int c  = lin & 127;
            Ls[c][kk] = f2bf(W[(b * 16 + kk) * 128 + c]);   // coalesced read
        }
        __syncthreads();
        #pragma unroll
        for (int i = 0; i < 8; ++i) {
            int lin = i * 256 + t;
            int c  = lin >> 4;           // 0..127
            int kk = lin & 15;
            Wt[c * 128 + b * 16 + kk] = Ls[c][kk];
        }
    } else {
        int idx = (b - 8) * 256 + t;     // 200 blocks cover 51200 >= 50000
        if (idx < N_NODES) cnt[idx] = 0;
    }
}

// ---------------------------------------------------------------------------
// Merged dispatch 1 (NO LDS anywhere -> full occupancy):
//  blocks [0, nGemm): support = inputs @ weight, bf16 MFMA. All 8 A-loads
//   hoisted into registers BEFORE convert/MFMA (r13 counters: FETCH 14.5MB
//   L3-resident at 1.2 TB/s = MLP-starved; VGPR=52 proved the compiler had
//   serialized the loads). B-frags read from global Wt (32KB, L1/L2-hot).
//  blocks [nGemm, ...): bucket scatter, XCD-partitioned (r9: 8x write amp
//   without), 784 blocks/group, 4 independent edge loads hoisted per thread.
// ---------------------------------------------------------------------------
#define SCAT_GROUPS 8
#define SCAT_BPG    784   // blocks per group; scatter grid = 8*784 = 6272
__global__ __launch_bounds__(256) void gemm_scatter_kernel(
    const float* __restrict__ inp, const short* __restrict__ Wt,
    short* __restrict__ support,
    const int* __restrict__ rows, const int* __restrict__ cols,
    const float* __restrict__ vals,
    int* __restrict__ cnt, int2* __restrict__ buckets, int nGemmBlocks)
{
    const int tid = threadIdx.x;
    if ((int)blockIdx.x >= nGemmBlocks) {
        // ---------------- bucket scatter ----------------
        const int sbid = (int)blockIdx.x - nGemmBlocks;
        const int g  = sbid & (SCAT_GROUPS - 1);
        const int gi = sbid >> 3;                   // 0..783
        const int rowLo = g * (N_NODES / SCAT_GROUPS);
        const int rowHi = rowLo + (N_NODES / SCAT_GROUPS);
        const int base = gi * 1024;                 // 784*1024 = 802816 >= E
        int e0 = base + tid, e1 = e0 + 256, e2 = e0 + 512, e3 = e0 + 768;
        // 4 independent coalesced row-loads in flight
        int r0 = (e0 < N_EDGES) ? rows[e0] : -1;
        int r1 = (e1 < N_EDGES) ? rows[e1] : -1;
        int r2 = (e2 < N_EDGES) ? rows[e2] : -1;
        int r3 = (e3 < N_EDGES) ? rows[e3] : -1;
        if (r0 >= rowLo && r0 < rowHi) {
            int p = atomicAdd(&cnt[r0], 1);
            if (p < CAP) buckets[(size_t)r0 * CAP + p] =
                make_int2(cols[e0], __float_as_int(vals[e0]));
        }
        if (r1 >= rowLo && r1 < rowHi) {
            int p = atomicAdd(&cnt[r1], 1);
            if (p < CAP) buckets[(size_t)r1 * CAP + p] =
                make_int2(cols[e1], __float_as_int(vals[e1]));
        }
        if (r2 >= rowLo && r2 < rowHi) {
            int p = atomicAdd(&cnt[r2], 1);
            if (p < CAP) buckets[(size_t)r2 * CAP + p] =
                make_int2(cols[e2], __float_as_int(vals[e2]));
        }
        if (r3 >= rowLo && r3 < rowHi) {
            int p = atomicAdd(&cnt[r3], 1);
            if (p < CAP) buckets[(size_t)r3 * CAP + p] =
                make_int2(cols[e3], __float_as_int(vals[e3]));
        }
        return;
    }

    // ---------------- GEMM (no LDS, hoisted A-loads) ----------------
    const int wid = tid >> 6, lane = tid & 63;
    const int lr = lane & 15;        // A-row / B-col / D-col
    const int lg = lane >> 4;        // k-group 0..3
    const int m0 = (int)blockIdx.x * 64 + wid * 16;

    int arow = m0 + lr;
    if (arow >= N_NODES) arow = 0;   // clamped rows feed only unstored D-rows
    const float* aptr = &inp[(size_t)arow * D + lg * 8];

    // all 8 A-loads issued before any use (32 VGPR, 8 in flight)
    float4 a[8];
    #pragma unroll
    for (int kc = 0; kc < 4; ++kc) {
        a[2 * kc + 0] = *(const float4*)(aptr + kc * 32);
        a[2 * kc + 1] = *(const float4*)(aptr + kc * 32 + 4);
    }
    bf16x8 af[4];
    #pragma unroll
    for (int kc = 0; kc < 4; ++kc) {
        af[kc][0] = f2bf(a[2*kc].x);   af[kc][1] = f2bf(a[2*kc].y);
        af[kc][2] = f2bf(a[2*kc].z);   af[kc][3] = f2bf(a[2*kc].w);
        af[kc][4] = f2bf(a[2*kc+1].x); af[kc][5] = f2bf(a[2*kc+1].y);
        af[kc][6] = f2bf(a[2*kc+1].z); af[kc][7] = f2bf(a[2*kc+1].w);
    }

    f32x4 acc[8] = {};
    #pragma unroll
    for (int kc = 0; kc < 4; ++kc) {
        #pragma unroll
        for (int t = 0; t < 8; ++t) {
            // B-frag elem j = W[k=kc*32+lg*8+j][c=t*16+lr] = Wt[c*128+k]
            const bf16x8 bf = *(const bf16x8*)&Wt[(t * 16 + lr) * 128 + kc * 32 + lg * 8];
            acc[t] = __builtin_amdgcn_mfma_f32_16x16x32_bf16(af[kc], bf, acc[t], 0, 0, 0);
        }
    }
    // D: col = lane&15, row = (lane>>4)*4 + reg; store bf16
    #pragma unroll
    for (int t = 0; t < 8; ++t) {
        #pragma unroll
        for (int r = 0; r < 4; ++r) {
            int orow = m0 + lg * 4 + r;
            if (orow < N_NODES)
                support[(size_t)orow * D + t * 16 + lr] = f2bf(acc[t][r]);
        }
    }
}

// ---------------------------------------------------------------------------
// Dispatch 2: per-row gather-reduce on bf16 support + fused epilogue
// (r10/r13-proven form). One wave per row; two 32-lane halves each own 4
// bf16 cols, 4-deep unroll = 8 gathers in flight; cross-half shfl reduce.
// ---------------------------------------------------------------------------
__global__ __launch_bounds__(256) void agg_fused(
    const short* __restrict__ support, const int* __restrict__ cnt,
    const int2* __restrict__ buckets,
    const float* __restrict__ inp, const float* __restrict__ bias,
    const float* __restrict__ alpha, float* __restrict__ out)
{
    const int wv = (blockIdx.x * 256 + threadIdx.x) >> 6;
    const int lane = threadIdx.x & 63;
    if (wv >= N_NODES) return;
    const int half = lane >> 5;
    const int li = lane & 31;

    int n = cnt[wv];
    if (n > CAP) n = CAP;
    const int start = wv * CAP;
    const int end   = start + n;

    const float4 x = *(const float4*)&inp[(size_t)wv * D + li * 4];
    const float4 b4 = *(const float4*)&bias[li * 4];
    const float a0 = alpha[0], a1 = alpha[1];

    float4 acc = make_float4(0.f, 0.f, 0.f, 0.f);
    int e = start;
    for (; e + 8 <= end; e += 8) {       // 4 gathers in flight per half
        int2 p0 = buckets[e + 0 + half];
        int2 p1 = buckets[e + 2 + half];
        int2 p2 = buckets[e + 4 + half];
        int2 p3 = buckets[e + 6 + half];
        short4v s0 = *(const short4v*)&support[(size_t)p0.x * D + li * 4];
        short4v s1 = *(const short4v*)&support[(size_t)p1.x * D + li * 4];
        short4v s2 = *(const short4v*)&support[(size_t)p2.x * D + li * 4];
        short4v s3 = *(const short4v*)&support[(size_t)p3.x * D + li * 4];
        float v0 = __int_as_float(p0.y), v1 = __int_as_float(p1.y);
        float v2 = __int_as_float(p2.y), v3 = __int_as_float(p3.y);
        acc.x += v0 * bf2f(s0[0]) + v1 * bf2f(s1[0]) + v2 * bf2f(s2[0]) + v3 * bf2f(s3[0]);
        acc.y += v0 * bf2f(s0[1]) + v1 * bf2f(s1[1]) + v2 * bf2f(s2[1]) + v3 * bf2f(s3[1]);
        acc.z += v0 * bf2f(s0[2]) + v1 * bf2f(s1[2]) + v2 * bf2f(s2[2]) + v3 * bf2f(s3[2]);
        acc.w += v0 * bf2f(s0[3]) + v1 * bf2f(s1[3]) + v2 * bf2f(s2[3]) + v3 * bf2f(s3[3]);
    }
    for (; e < end; e += 2) {
        int idx = e + half;
        int2 p = (idx < end) ? buckets[idx] : make_int2(0, 0);  // v=0 when invalid
        float v = __int_as_float(p.y);
        short4v s = *(const short4v*)&support[(size_t)p.x * D + li * 4];
        acc.x += v * bf2f(s[0]);
        acc.y += v * bf2f(s[1]);
        acc.z += v * bf2f(s[2]);
        acc.w += v * bf2f(s[3]);
    }

    acc.x += __shfl_xor(acc.x, 32);
    acc.y += __shfl_xor(acc.y, 32);
    acc.z += __shfl_xor(acc.z, 32);
    acc.w += __shfl_xor(acc.w, 32);

    const float m = fmaxf(a0, a1);
    const float e0 = __expf(a0 - m), e1 = __expf(a1 - m);
    const float inv = 1.f / (e0 + e1);
    const float g0 = e0 * inv, g1 = e1 * inv;

    float t0 = acc.x * g0 + x.x * g1 + b4.x;
    float t1 = acc.y * g0 + x.y * g1 + b4.y;
    float t2 = acc.z * g0 + x.z * g1 + b4.z;
    float t3 = acc.w * g0 + x.w * g1 + b4.w;
    float r0 = t0 > 0.f ? t0 : (__expf(t0) - 1.f);
    float r1 = t1 > 0.f ? t1 : (__expf(t1) - 1.f);
    float r2 = t2 > 0.f ? t2 : (__expf(t2) - 1.f);
    float r3 = t3 > 0.f ? t3 : (__expf(t3) - 1.f);

    float2 o = (half == 0) ? make_float2(r0, r1) : make_float2(r2, r3);
    *(float2*)&out[(size_t)wv * D + li * 4 + half * 2] = o;
}

extern "C" void kernel_launch(void* const* d_in, const int* in_sizes, int n_in,
                              void* d_out, int out_size, void* d_ws, size_t ws_size,
                              hipStream_t stream)
{
    const float* inp   = (const float*)d_in[0];
    const float* W     = (const float*)d_in[1];
    const float* bias  = (const float*)d_in[2];
    const float* alpha = (const float*)d_in[3];
    const float* vals  = (const float*)d_in[4];
    const int*   rows  = (const int*)d_in[5];
    const int*   cols  = (const int*)d_in[6];
    float* out = (float*)d_out;

    // workspace layout (~64.4 MB; no trailing backslashes in comments)
    short* support = (short*)d_ws;                            // N*D bf16
    short* Wt      = support + (size_t)N_NODES * D;           // 128*128 bf16
    int*   cnt     = (int*)(Wt + 128 * 128);                  // N ints (zeroed by prep)
    // counts so far even -> buckets 8B-aligned
    int2*  buckets = (int2*)(cnt + N_NODES);                  // N*CAP pairs, 51.2 MB

    const int nGemmBlocks = (N_NODES + 63) / 64;              // 782
    const int nScatBlocks = SCAT_GROUPS * SCAT_BPG;           // 6272

    prep_zero<<<8 + (N_NODES + 255) / 256, 256, 0, stream>>>(W, Wt, cnt);
    gemm_scatter_kernel<<<nGemmBlocks + nScatBlocks, 256, 0, stream>>>(
        inp, Wt, support, rows, cols, vals, cnt, buckets, nGemmBlocks);
    agg_fused<<<(N_NODES * 64 + 255) / 256, 256, 0, stream>>>(
        support, cnt, buckets, inp, bias, alpha, out);
}